// Round 7
// baseline (119.015 us; speedup 1.0000x reference)
//
#include <hip/hip_runtime.h>

#define B 8
#define H 256
#define W 512
#define C 16
#define FIL 16
#define NP 8
#define PH 32      // H/NP
#define W2 256     // W/2
#define CH 8       // width chunks for pool kernel
#define POOL_ELEMS (B*NP*W2*C)   // 327680 floats

typedef float f32x4 __attribute__((ext_vector_type(4)));

// ---------------- Kernel 1: average pool (32x2), H-split partials ---------
__global__ __launch_bounds__(256) void pool_kernel(const float* __restrict__ fm,
                                                   float* __restrict__ PP) {
    int blk = blockIdx.x;
    int rh = blk & 1;
    int ch = (blk >> 1) & (CH - 1);
    int bi = blk >> 4;               // b*NP + i
    int t = threadIdx.x;
    const float4* src = (const float4*)fm + (size_t)bi * (PH * W * C / 4)
                        + rh * 16 * (W * C / 4) + ch * 256 + t;
    float4 acc = make_float4(0.f, 0.f, 0.f, 0.f);
#pragma unroll 16
    for (int hh = 0; hh < 16; ++hh) {
        float4 v = src[hh * (W * C / 4)];
        acc.x += v.x; acc.y += v.y; acc.z += v.z; acc.w += v.w;
    }
    __shared__ float4 s[256];
    s[t] = acc;
    __syncthreads();
    if (t < 128) {
        int u = t >> 2, q = t & 3;        // pooled-pixel-local, channel quad
        float4 a = s[u * 8 + q], b2 = s[u * 8 + 4 + q];
        float4 r = make_float4((a.x + b2.x) * (1.0f / 64.0f),
                               (a.y + b2.y) * (1.0f / 64.0f),
                               (a.z + b2.z) * (1.0f / 64.0f),
                               (a.w + b2.w) * (1.0f / 64.0f));
        float4* out = (float4*)(PP + (size_t)rh * POOL_ELEMS + (size_t)bi * (W2 * C))
                      + ch * 128 + t;
        *out = r;
    }
}

// ---------------- Kernel 2: masked 5x5 conv (rows 0,4 only), row + col ----
__global__ __launch_bounds__(256) void conv_kernel(const float* __restrict__ PP,
                                                   const float* __restrict__ kern,
                                                   const float* __restrict__ bias,
                                                   float* __restrict__ ROW,
                                                   float* __restrict__ COL) {
    int blk = blockIdx.x;
    int part = blk & 3;
    int bi = blk >> 2;
    int b = bi >> 3, i = bi & 7;
    int t = threadIdx.x;
    __shared__ float K0[5 * C * FIL];    // kernel row r=0
    __shared__ float K4[5 * C * FIL];    // kernel row r=4
    for (int idx = t; idx < 5 * C * FIL; idx += 256) {
        K0[idx] = kern[idx];                     // r=0 at offset 0
        K4[idx] = kern[4 * 5 * C * FIL + idx];   // r=4
    }
    __syncthreads();
    bool is_row = (part < 2);
    int jhalf = part & 1;
    int j = jhalf * 128 + (t >> 1);
    int fh = (t & 1) * 8;
    const float* Pb0 = PP + (size_t)b * (NP * W2 * C);
    const float* Pb1 = Pb0 + POOL_ELEMS;
    float acc[8];
#pragma unroll
    for (int f = 0; f < 8; ++f) acc[f] = bias[fh + f];

    if (is_row) {
#pragma unroll
        for (int rr = 0; rr < 2; ++rr) {
            int ii = i + (rr ? 2 : -2);
            if (ii < 0 || ii >= NP) continue;
            const float* Kr = (rr ? K4 : K0) + fh;
            for (int s = 0; s < 5; ++s) {
                int jj = j + s - 2;
                if (jj < 0 || jj >= W2) continue;
                const float4* p40 = (const float4*)(Pb0 + (size_t)(ii * W2 + jj) * C);
                const float4* p41 = (const float4*)(Pb1 + (size_t)(ii * W2 + jj) * C);
#pragma unroll
                for (int cq = 0; cq < 4; ++cq) {
                    float4 pa = p40[cq], pb = p41[cq];
                    float4 pv = make_float4(pa.x + pb.x, pa.y + pb.y,
                                            pa.z + pb.z, pa.w + pb.w);
                    const float* kk = Kr + (s * C + cq * 4) * FIL;
#pragma unroll
                    for (int f = 0; f < 8; ++f) {
                        acc[f] = fmaf(pv.x, kk[f], acc[f]);
                        acc[f] = fmaf(pv.y, kk[FIL + f], acc[f]);
                        acc[f] = fmaf(pv.z, kk[2 * FIL + f], acc[f]);
                        acc[f] = fmaf(pv.w, kk[3 * FIL + f], acc[f]);
                    }
                }
            }
        }
        float* o = ROW + ((size_t)(b * NP + i) * W2 + j) * FIL + fh;
#pragma unroll
        for (int f = 0; f < 8; ++f) o[f] = fmaxf(acc[f], 0.0f);
    } else {
        for (int s = 0; s < 5; ++s) {
            int ii = i + s - 2;
            if (ii < 0 || ii >= NP) continue;
#pragma unroll
            for (int rr = 0; rr < 2; ++rr) {
                int jj = j + (rr ? 2 : -2);
                if (jj < 0 || jj >= W2) continue;
                const float* Kr = (rr ? K4 : K0) + fh;
                const float4* p40 = (const float4*)(Pb0 + (size_t)(ii * W2 + jj) * C);
                const float4* p41 = (const float4*)(Pb1 + (size_t)(ii * W2 + jj) * C);
#pragma unroll
                for (int cq = 0; cq < 4; ++cq) {
                    float4 pa = p40[cq], pb = p41[cq];
                    float4 pv = make_float4(pa.x + pb.x, pa.y + pb.y,
                                            pa.z + pb.z, pa.w + pb.w);
                    const float* kk = Kr + (s * C + cq * 4) * FIL;
#pragma unroll
                    for (int f = 0; f < 8; ++f) {
                        acc[f] = fmaf(pv.x, kk[f], acc[f]);
                        acc[f] = fmaf(pv.y, kk[FIL + f], acc[f]);
                        acc[f] = fmaf(pv.z, kk[2 * FIL + f], acc[f]);
                        acc[f] = fmaf(pv.w, kk[3 * FIL + f], acc[f]);
                    }
                }
            }
        }
        float* o = COL + ((size_t)(b * NP + i) * W2 + j) * FIL + fh;
#pragma unroll
        for (int f = 0; f < 8; ++f) o[f] = fmaxf(acc[f], 0.0f);
    }
}

// ---------------- Kernel 3: bilinear upsample + diff + concat -------------
__global__ __launch_bounds__(384) void up_kernel(const float* __restrict__ fm,
                                                 const float* __restrict__ ROW,
                                                 const float* __restrict__ COL,
                                                 float* __restrict__ out) {
    int bid = blockIdx.x;
    int blk = (bid & 7) * 256 + (bid >> 3);   // bijective: XCD k -> b = k
    int b = blk >> 8, h = blk & 255;
    int t = threadIdx.x;
    __shared__ float Rs[W2 * C];   // H-lerped row_op row
    __shared__ float Cs[W2 * C];   // H-lerped col_op row

    float sh = (h + 0.5f) * (1.0f / 32.0f) - 0.5f;
    float flh = floorf(sh);
    float fh = sh - flh;
    int i0 = (int)flh;
    int i1 = min(i0 + 1, NP - 1);
    i0 = max(i0, 0);
    float wa = 1.0f - fh, wb = fh;

    const float4* r0 = (const float4*)(ROW + (size_t)(b * NP + i0) * (W2 * C));
    const float4* r1 = (const float4*)(ROW + (size_t)(b * NP + i1) * (W2 * C));
    const float4* c0 = (const float4*)(COL + (size_t)(b * NP + i0) * (W2 * C));
    const float4* c1 = (const float4*)(COL + (size_t)(b * NP + i1) * (W2 * C));
    for (int idx = t; idx < W2 * C / 4; idx += 384) {
        float4 a = r0[idx], bv = r1[idx];
        ((float4*)Rs)[idx] = make_float4(wa * a.x + wb * bv.x, wa * a.y + wb * bv.y,
                                         wa * a.z + wb * bv.z, wa * a.w + wb * bv.w);
        float4 ca = c0[idx], cb = c1[idx];
        ((float4*)Cs)[idx] = make_float4(wa * ca.x + wb * cb.x, wa * ca.y + wb * cb.y,
                                         wa * ca.z + wb * cb.z, wa * ca.w + wb * cb.w);
    }
    __syncthreads();

    int p_local = t / 12;          // 0..31, computed once
    int q = t - p_local * 12;      // 0..11, fixed per thread
    int cc = (q & 3) * 4;
    bool is_copy = (q < 4);
    const float* S = (q < 8) ? Rs : Cs;

    const float4* fmr = (const float4*)(fm + (size_t)(b * H + h) * (W * C));
    float4* orow = (float4*)(out + (size_t)(b * H + h) * (W * 48));
#pragma unroll
    for (int k = 0; k < 16; ++k) {
        int p = k * 32 + p_local;
        float4 v = fmr[p * 4 + (q & 3)];
        if (!is_copy) {
            float sw = 0.5f * p - 0.25f;
            float flw = floorf(sw);
            float fw = sw - flw;
            int j0i = max((int)flw, 0);
            int j1i = min((int)flw + 1, W2 - 1);
            const float* A  = S + j0i * 16 + cc;
            const float* Bv = S + j1i * 16 + cc;
            float iw = 1.0f - fw;
            v.x -= iw * A[0] + fw * Bv[0];
            v.y -= iw * A[1] + fw * Bv[1];
            v.z -= iw * A[2] + fw * Bv[2];
            v.w -= iw * A[3] + fw * Bv[3];
        }
        orow[(size_t)p * 12 + q] = v;
    }
}

extern "C" void kernel_launch(void* const* d_in, const int* in_sizes, int n_in,
                              void* d_out, int out_size, void* d_ws, size_t ws_size,
                              hipStream_t stream) {
    const float* fm   = (const float*)d_in[0];
    const float* kern = (const float*)d_in[1];
    const float* bias = (const float*)d_in[2];
    float* out = (float*)d_out;
    float* PP  = (float*)d_ws;                 // 2 x POOL_ELEMS partials
    float* ROW = PP + 2 * POOL_ELEMS;
    float* COL = ROW + POOL_ELEMS;

    pool_kernel<<<B * NP * CH * 2, 256, 0, stream>>>(fm, PP);
    conv_kernel<<<B * NP * 4, 256, 0, stream>>>(PP, kern, bias, ROW, COL);
    // DIAGNOSTIC ROUND: up launched TWICE (idempotent — same inputs, same
    // output values). dur_new - 67.05 isolates U_warm, the L3-warm cost of
    // the upsample/diff kernel, which the fill-dominated profile hides.
    up_kernel<<<B * H, 384, 0, stream>>>(fm, ROW, COL, out);
    up_kernel<<<B * H, 384, 0, stream>>>(fm, ROW, COL, out);
}

// Round 8
// 64.494 us; speedup vs baseline: 1.8453x; 1.8453x over previous
//
#include <hip/hip_runtime.h>

#define B 8
#define H 256
#define W 512
#define C 16
#define FIL 16
#define NP 8
#define PH 32      // H/NP
#define W2 256     // W/2
#define CH 8       // width chunks for pool kernel
#define POOL_ELEMS (B*NP*W2*C)   // 327680 floats

// ---------------- Kernel 1: average pool (32x2), H-split partials ---------
__global__ __launch_bounds__(256) void pool_kernel(const float* __restrict__ fm,
                                                   float* __restrict__ PP) {
    int blk = blockIdx.x;
    int rh = blk & 1;
    int ch = (blk >> 1) & (CH - 1);
    int bi = blk >> 4;               // b*NP + i
    int t = threadIdx.x;
    const float4* src = (const float4*)fm + (size_t)bi * (PH * W * C / 4)
                        + rh * 16 * (W * C / 4) + ch * 256 + t;
    float4 acc = make_float4(0.f, 0.f, 0.f, 0.f);
#pragma unroll 16
    for (int hh = 0; hh < 16; ++hh) {
        float4 v = src[hh * (W * C / 4)];
        acc.x += v.x; acc.y += v.y; acc.z += v.z; acc.w += v.w;
    }
    __shared__ float4 s[256];
    s[t] = acc;
    __syncthreads();
    if (t < 128) {
        int u = t >> 2, q = t & 3;        // pooled-pixel-local, channel quad
        float4 a = s[u * 8 + q], b2 = s[u * 8 + 4 + q];
        float4 r = make_float4((a.x + b2.x) * (1.0f / 64.0f),
                               (a.y + b2.y) * (1.0f / 64.0f),
                               (a.z + b2.z) * (1.0f / 64.0f),
                               (a.w + b2.w) * (1.0f / 64.0f));
        float4* out = (float4*)(PP + (size_t)rh * POOL_ELEMS + (size_t)bi * (W2 * C))
                      + ch * 128 + t;
        *out = r;
    }
}

// ---------------- Kernel 2: masked 5x5 conv (rows 0,4 only), row + col ----
__global__ __launch_bounds__(256) void conv_kernel(const float* __restrict__ PP,
                                                   const float* __restrict__ kern,
                                                   const float* __restrict__ bias,
                                                   float* __restrict__ ROW,
                                                   float* __restrict__ COL) {
    int blk = blockIdx.x;
    int part = blk & 3;
    int bi = blk >> 2;
    int b = bi >> 3, i = bi & 7;
    int t = threadIdx.x;
    __shared__ float K0[5 * C * FIL];    // kernel row r=0
    __shared__ float K4[5 * C * FIL];    // kernel row r=4
    for (int idx = t; idx < 5 * C * FIL; idx += 256) {
        K0[idx] = kern[idx];                     // r=0 at offset 0
        K4[idx] = kern[4 * 5 * C * FIL + idx];   // r=4
    }
    __syncthreads();
    bool is_row = (part < 2);
    int jhalf = part & 1;
    int j = jhalf * 128 + (t >> 1);
    int fh = (t & 1) * 8;
    const float* Pb0 = PP + (size_t)b * (NP * W2 * C);
    const float* Pb1 = Pb0 + POOL_ELEMS;
    float acc[8];
#pragma unroll
    for (int f = 0; f < 8; ++f) acc[f] = bias[fh + f];

    if (is_row) {
#pragma unroll
        for (int rr = 0; rr < 2; ++rr) {
            int ii = i + (rr ? 2 : -2);
            if (ii < 0 || ii >= NP) continue;
            const float* Kr = (rr ? K4 : K0) + fh;
            for (int s = 0; s < 5; ++s) {
                int jj = j + s - 2;
                if (jj < 0 || jj >= W2) continue;
                const float4* p40 = (const float4*)(Pb0 + (size_t)(ii * W2 + jj) * C);
                const float4* p41 = (const float4*)(Pb1 + (size_t)(ii * W2 + jj) * C);
#pragma unroll
                for (int cq = 0; cq < 4; ++cq) {
                    float4 pa = p40[cq], pb = p41[cq];
                    float4 pv = make_float4(pa.x + pb.x, pa.y + pb.y,
                                            pa.z + pb.z, pa.w + pb.w);
                    const float* kk = Kr + (s * C + cq * 4) * FIL;
#pragma unroll
                    for (int f = 0; f < 8; ++f) {
                        acc[f] = fmaf(pv.x, kk[f], acc[f]);
                        acc[f] = fmaf(pv.y, kk[FIL + f], acc[f]);
                        acc[f] = fmaf(pv.z, kk[2 * FIL + f], acc[f]);
                        acc[f] = fmaf(pv.w, kk[3 * FIL + f], acc[f]);
                    }
                }
            }
        }
        float* o = ROW + ((size_t)(b * NP + i) * W2 + j) * FIL + fh;
#pragma unroll
        for (int f = 0; f < 8; ++f) o[f] = fmaxf(acc[f], 0.0f);
    } else {
        for (int s = 0; s < 5; ++s) {
            int ii = i + s - 2;
            if (ii < 0 || ii >= NP) continue;
#pragma unroll
            for (int rr = 0; rr < 2; ++rr) {
                int jj = j + (rr ? 2 : -2);
                if (jj < 0 || jj >= W2) continue;
                const float* Kr = (rr ? K4 : K0) + fh;
                const float4* p40 = (const float4*)(Pb0 + (size_t)(ii * W2 + jj) * C);
                const float4* p41 = (const float4*)(Pb1 + (size_t)(ii * W2 + jj) * C);
#pragma unroll
                for (int cq = 0; cq < 4; ++cq) {
                    float4 pa = p40[cq], pb = p41[cq];
                    float4 pv = make_float4(pa.x + pb.x, pa.y + pb.y,
                                            pa.z + pb.z, pa.w + pb.w);
                    const float* kk = Kr + (s * C + cq * 4) * FIL;
#pragma unroll
                    for (int f = 0; f < 8; ++f) {
                        acc[f] = fmaf(pv.x, kk[f], acc[f]);
                        acc[f] = fmaf(pv.y, kk[FIL + f], acc[f]);
                        acc[f] = fmaf(pv.z, kk[2 * FIL + f], acc[f]);
                        acc[f] = fmaf(pv.w, kk[3 * FIL + f], acc[f]);
                    }
                }
            }
        }
        float* o = COL + ((size_t)(b * NP + i) * W2 + j) * FIL + fh;
#pragma unroll
        for (int f = 0; f < 8; ++f) o[f] = fmaxf(acc[f], 0.0f);
    }
}

// ---------------- Kernel 3: bilinear upsample + diff + concat -------------
// grid = B*H blocks (XCD-swizzled), 256 threads. Thread = (pixel p, quad cq):
// ONE fm load -> THREE stores (copy, fm-row_up, fm-col_up). 3x fewer global
// loads than the slot-per-thread layout; uniform control flow (no is_copy
// divergence). 8 units per thread.
__global__ __launch_bounds__(256) void up_kernel(const float* __restrict__ fm,
                                                 const float* __restrict__ ROW,
                                                 const float* __restrict__ COL,
                                                 float* __restrict__ out) {
    int bid = blockIdx.x;
    int blk = (bid & 7) * 256 + (bid >> 3);   // bijective: XCD k -> b = k
    int b = blk >> 8, h = blk & 255;
    int t = threadIdx.x;
    __shared__ float Rs[W2 * C];   // H-lerped row_op row
    __shared__ float Cs[W2 * C];   // H-lerped col_op row

    float sh = (h + 0.5f) * (1.0f / 32.0f) - 0.5f;
    float flh = floorf(sh);
    float fh = sh - flh;
    int i0 = (int)flh;
    int i1 = min(i0 + 1, NP - 1);
    i0 = max(i0, 0);
    float wa = 1.0f - fh, wb = fh;

    const float4* r0 = (const float4*)(ROW + (size_t)(b * NP + i0) * (W2 * C));
    const float4* r1 = (const float4*)(ROW + (size_t)(b * NP + i1) * (W2 * C));
    const float4* c0 = (const float4*)(COL + (size_t)(b * NP + i0) * (W2 * C));
    const float4* c1 = (const float4*)(COL + (size_t)(b * NP + i1) * (W2 * C));
#pragma unroll
    for (int k = 0; k < 4; ++k) {
        int idx = t + k * 256;
        float4 a = r0[idx], bv = r1[idx];
        ((float4*)Rs)[idx] = make_float4(wa * a.x + wb * bv.x, wa * a.y + wb * bv.y,
                                         wa * a.z + wb * bv.z, wa * a.w + wb * bv.w);
        float4 ca = c0[idx], cb = c1[idx];
        ((float4*)Cs)[idx] = make_float4(wa * ca.x + wb * cb.x, wa * ca.y + wb * cb.y,
                                         wa * ca.z + wb * cb.z, wa * ca.w + wb * cb.w);
    }
    __syncthreads();

    int cq = t & 3;                // channel quad 0..3
    int p0 = t >> 2;               // 0..63
    int cc = cq * 4;

    const float4* fmr = (const float4*)(fm + (size_t)(b * H + h) * (W * C));
    float4* orow = (float4*)(out + (size_t)(b * H + h) * (W * 48));
#pragma unroll
    for (int k = 0; k < 8; ++k) {
        int p = k * 64 + p0;
        float4 v = fmr[p * 4 + cq];

        float sw = 0.5f * p - 0.25f;
        float flw = floorf(sw);
        float fw = sw - flw;
        int j0i = max((int)flw, 0);
        int j1i = min((int)flw + 1, W2 - 1);
        float iw = 1.0f - fw;

        const float4 Ra = *(const float4*)(Rs + j0i * 16 + cc);
        const float4 Rb = *(const float4*)(Rs + j1i * 16 + cc);
        const float4 Ca = *(const float4*)(Cs + j0i * 16 + cc);
        const float4 Cb = *(const float4*)(Cs + j1i * 16 + cc);

        float4 dr = make_float4(v.x - (iw * Ra.x + fw * Rb.x),
                                v.y - (iw * Ra.y + fw * Rb.y),
                                v.z - (iw * Ra.z + fw * Rb.z),
                                v.w - (iw * Ra.w + fw * Rb.w));
        float4 dc = make_float4(v.x - (iw * Ca.x + fw * Cb.x),
                                v.y - (iw * Ca.y + fw * Cb.y),
                                v.z - (iw * Ca.z + fw * Cb.z),
                                v.w - (iw * Ca.w + fw * Cb.w));

        orow[p * 12 + cq]     = v;    // channels 0..15: copy
        orow[p * 12 + 4 + cq] = dr;   // channels 16..31: fm - row_up
        orow[p * 12 + 8 + cq] = dc;   // channels 32..47: fm - col_up
    }
}

extern "C" void kernel_launch(void* const* d_in, const int* in_sizes, int n_in,
                              void* d_out, int out_size, void* d_ws, size_t ws_size,
                              hipStream_t stream) {
    const float* fm   = (const float*)d_in[0];
    const float* kern = (const float*)d_in[1];
    const float* bias = (const float*)d_in[2];
    float* out = (float*)d_out;
    float* PP  = (float*)d_ws;                 // 2 x POOL_ELEMS partials
    float* ROW = PP + 2 * POOL_ELEMS;
    float* COL = ROW + POOL_ELEMS;

    pool_kernel<<<B * NP * CH * 2, 256, 0, stream>>>(fm, PP);
    conv_kernel<<<B * NP * 4, 256, 0, stream>>>(PP, kern, bias, ROW, COL);
    up_kernel<<<B * H, 256, 0, stream>>>(fm, ROW, COL, out);
}

// Round 9
// 64.376 us; speedup vs baseline: 1.8488x; 1.0018x over previous
//
#include <hip/hip_runtime.h>

#define B 8
#define H 256
#define W 512
#define C 16
#define FIL 16
#define NP 8
#define PH 32      // H/NP
#define W2 256     // W/2
#define CH 8       // width chunks for pool kernel
#define POOL_ELEMS (B*NP*W2*C)   // 327680 floats

// ---------------- Kernel 1: average pool (32x2), H-split partials ---------
__global__ __launch_bounds__(256) void pool_kernel(const float* __restrict__ fm,
                                                   float* __restrict__ PP) {
    int blk = blockIdx.x;
    int rh = blk & 1;
    int ch = (blk >> 1) & (CH - 1);
    int bi = blk >> 4;               // b*NP + i
    int t = threadIdx.x;
    const float4* src = (const float4*)fm + (size_t)bi * (PH * W * C / 4)
                        + rh * 16 * (W * C / 4) + ch * 256 + t;
    float4 acc = make_float4(0.f, 0.f, 0.f, 0.f);
#pragma unroll 16
    for (int hh = 0; hh < 16; ++hh) {
        float4 v = src[hh * (W * C / 4)];
        acc.x += v.x; acc.y += v.y; acc.z += v.z; acc.w += v.w;
    }
    __shared__ float4 s[256];
    s[t] = acc;
    __syncthreads();
    if (t < 128) {
        int u = t >> 2, q = t & 3;        // pooled-pixel-local, channel quad
        float4 a = s[u * 8 + q], b2 = s[u * 8 + 4 + q];
        float4 r = make_float4((a.x + b2.x) * (1.0f / 64.0f),
                               (a.y + b2.y) * (1.0f / 64.0f),
                               (a.z + b2.z) * (1.0f / 64.0f),
                               (a.w + b2.w) * (1.0f / 64.0f));
        float4* out = (float4*)(PP + (size_t)rh * POOL_ELEMS + (size_t)bi * (W2 * C))
                      + ch * 128 + t;
        *out = r;
    }
}

// ---------------- Kernel 2: masked 5x5 conv (rows 0,4 only), row + col ----
// grid = 64 bands x {row,col} x 4 j-quarters = 512 blocks, 256 threads.
// thread = (pixel px 0..63, filter-quad fq). 640 FMA/thread.
__global__ __launch_bounds__(256) void conv_kernel(const float* __restrict__ PP,
                                                   const float* __restrict__ kern,
                                                   const float* __restrict__ bias,
                                                   float* __restrict__ ROW,
                                                   float* __restrict__ COL) {
    int blk = blockIdx.x;
    int jq = blk & 3;
    int rc = (blk >> 2) & 1;
    int bi = blk >> 3;               // 0..63
    int b = bi >> 3, i = bi & 7;
    int t = threadIdx.x;
    __shared__ float K0[5 * C * FIL];    // kernel row r=0
    __shared__ float K4[5 * C * FIL];    // kernel row r=4
    for (int idx = t; idx < 5 * C * FIL; idx += 256) {
        K0[idx] = kern[idx];
        K4[idx] = kern[4 * 5 * C * FIL + idx];
    }
    __syncthreads();
    int px = t >> 2;
    int j = jq * 64 + px;
    int fq = (t & 3) * 4;
    const float* Pb0 = PP + (size_t)b * (NP * W2 * C);
    const float* Pb1 = Pb0 + POOL_ELEMS;
    float acc0 = bias[fq], acc1 = bias[fq + 1], acc2 = bias[fq + 2], acc3 = bias[fq + 3];

    if (rc == 0) {
        // row_op: rows i-2 (K0), i+2 (K4); cols j+s-2
#pragma unroll
        for (int rr = 0; rr < 2; ++rr) {
            int ii = i + (rr ? 2 : -2);
            if (ii < 0 || ii >= NP) continue;
            const float* Kr = (rr ? K4 : K0) + fq;
            for (int s = 0; s < 5; ++s) {
                int jj = j + s - 2;
                if (jj < 0 || jj >= W2) continue;
                const float4* p40 = (const float4*)(Pb0 + (size_t)(ii * W2 + jj) * C);
                const float4* p41 = (const float4*)(Pb1 + (size_t)(ii * W2 + jj) * C);
#pragma unroll
                for (int cq = 0; cq < 4; ++cq) {
                    float4 pa = p40[cq], pb = p41[cq];
                    float4 pv = make_float4(pa.x + pb.x, pa.y + pb.y,
                                            pa.z + pb.z, pa.w + pb.w);
                    const float* kk = Kr + (s * C + cq * 4) * FIL;
                    acc0 = fmaf(pv.x, kk[0], acc0); acc1 = fmaf(pv.x, kk[1], acc1);
                    acc2 = fmaf(pv.x, kk[2], acc2); acc3 = fmaf(pv.x, kk[3], acc3);
                    acc0 = fmaf(pv.y, kk[FIL + 0], acc0); acc1 = fmaf(pv.y, kk[FIL + 1], acc1);
                    acc2 = fmaf(pv.y, kk[FIL + 2], acc2); acc3 = fmaf(pv.y, kk[FIL + 3], acc3);
                    acc0 = fmaf(pv.z, kk[2 * FIL + 0], acc0); acc1 = fmaf(pv.z, kk[2 * FIL + 1], acc1);
                    acc2 = fmaf(pv.z, kk[2 * FIL + 2], acc2); acc3 = fmaf(pv.z, kk[2 * FIL + 3], acc3);
                    acc0 = fmaf(pv.w, kk[3 * FIL + 0], acc0); acc1 = fmaf(pv.w, kk[3 * FIL + 1], acc1);
                    acc2 = fmaf(pv.w, kk[3 * FIL + 2], acc2); acc3 = fmaf(pv.w, kk[3 * FIL + 3], acc3);
                }
            }
        }
        float4* o = (float4*)(ROW + ((size_t)(b * NP + i) * W2 + j) * FIL + fq);
        *o = make_float4(fmaxf(acc0, 0.f), fmaxf(acc1, 0.f), fmaxf(acc2, 0.f), fmaxf(acc3, 0.f));
    } else {
        // col_op: rows i+s-2; cols j-2 (K0), j+2 (K4)
        for (int s = 0; s < 5; ++s) {
            int ii = i + s - 2;
            if (ii < 0 || ii >= NP) continue;
#pragma unroll
            for (int rr = 0; rr < 2; ++rr) {
                int jj = j + (rr ? 2 : -2);
                if (jj < 0 || jj >= W2) continue;
                const float* Kr = (rr ? K4 : K0) + fq;
                const float4* p40 = (const float4*)(Pb0 + (size_t)(ii * W2 + jj) * C);
                const float4* p41 = (const float4*)(Pb1 + (size_t)(ii * W2 + jj) * C);
#pragma unroll
                for (int cq = 0; cq < 4; ++cq) {
                    float4 pa = p40[cq], pb = p41[cq];
                    float4 pv = make_float4(pa.x + pb.x, pa.y + pb.y,
                                            pa.z + pb.z, pa.w + pb.w);
                    const float* kk = Kr + (s * C + cq * 4) * FIL;
                    acc0 = fmaf(pv.x, kk[0], acc0); acc1 = fmaf(pv.x, kk[1], acc1);
                    acc2 = fmaf(pv.x, kk[2], acc2); acc3 = fmaf(pv.x, kk[3], acc3);
                    acc0 = fmaf(pv.y, kk[FIL + 0], acc0); acc1 = fmaf(pv.y, kk[FIL + 1], acc1);
                    acc2 = fmaf(pv.y, kk[FIL + 2], acc2); acc3 = fmaf(pv.y, kk[FIL + 3], acc3);
                    acc0 = fmaf(pv.z, kk[2 * FIL + 0], acc0); acc1 = fmaf(pv.z, kk[2 * FIL + 1], acc1);
                    acc2 = fmaf(pv.z, kk[2 * FIL + 2], acc2); acc3 = fmaf(pv.z, kk[2 * FIL + 3], acc3);
                    acc0 = fmaf(pv.w, kk[3 * FIL + 0], acc0); acc1 = fmaf(pv.w, kk[3 * FIL + 1], acc1);
                    acc2 = fmaf(pv.w, kk[3 * FIL + 2], acc2); acc3 = fmaf(pv.w, kk[3 * FIL + 3], acc3);
                }
            }
        }
        float4* o = (float4*)(COL + ((size_t)(b * NP + i) * W2 + j) * FIL + fq);
        *o = make_float4(fmaxf(acc0, 0.f), fmaxf(acc1, 0.f), fmaxf(acc2, 0.f), fmaxf(acc3, 0.f));
    }
}

// ---------------- Kernel 3: bilinear upsample + diff + concat -------------
// grid = B*H blocks (XCD-swizzled), 256 threads. Thread = (pixel, quad):
// one fm load -> three outputs. k-PAIRED: issue 2 loads, compute 6 vectors,
// then 6 back-to-back stores (longer write bursts against the read stream).
__global__ __launch_bounds__(256) void up_kernel(const float* __restrict__ fm,
                                                 const float* __restrict__ ROW,
                                                 const float* __restrict__ COL,
                                                 float* __restrict__ out) {
    int bid = blockIdx.x;
    int blk = (bid & 7) * 256 + (bid >> 3);   // bijective: XCD k -> b = k
    int b = blk >> 8, h = blk & 255;
    int t = threadIdx.x;
    __shared__ float Rs[W2 * C];   // H-lerped row_op row
    __shared__ float Cs[W2 * C];   // H-lerped col_op row

    float sh = (h + 0.5f) * (1.0f / 32.0f) - 0.5f;
    float flh = floorf(sh);
    float fh = sh - flh;
    int i0 = (int)flh;
    int i1 = min(i0 + 1, NP - 1);
    i0 = max(i0, 0);
    float wa = 1.0f - fh, wb = fh;

    const float4* r0 = (const float4*)(ROW + (size_t)(b * NP + i0) * (W2 * C));
    const float4* r1 = (const float4*)(ROW + (size_t)(b * NP + i1) * (W2 * C));
    const float4* c0 = (const float4*)(COL + (size_t)(b * NP + i0) * (W2 * C));
    const float4* c1 = (const float4*)(COL + (size_t)(b * NP + i1) * (W2 * C));
#pragma unroll
    for (int k = 0; k < 4; ++k) {
        int idx = t + k * 256;
        float4 a = r0[idx], bv = r1[idx];
        ((float4*)Rs)[idx] = make_float4(wa * a.x + wb * bv.x, wa * a.y + wb * bv.y,
                                         wa * a.z + wb * bv.z, wa * a.w + wb * bv.w);
        float4 ca = c0[idx], cb = c1[idx];
        ((float4*)Cs)[idx] = make_float4(wa * ca.x + wb * cb.x, wa * ca.y + wb * cb.y,
                                         wa * ca.z + wb * cb.z, wa * ca.w + wb * cb.w);
    }
    __syncthreads();

    int cq = t & 3;                // channel quad 0..3
    int p0 = t >> 2;               // 0..63
    int cc = cq * 4;

    const float4* fmr = (const float4*)(fm + (size_t)(b * H + h) * (W * C));
    float4* orow = (float4*)(out + (size_t)(b * H + h) * (W * 48));
#pragma unroll
    for (int kk2 = 0; kk2 < 4; ++kk2) {
        int pA = kk2 * 128 + p0;
        int pB = pA + 64;
        float4 vA = fmr[pA * 4 + cq];
        float4 vB = fmr[pB * 4 + cq];

        float swA = 0.5f * pA - 0.25f;
        float flwA = floorf(swA);
        float fwA = swA - flwA;
        int j0A = max((int)flwA, 0);
        int j1A = min((int)flwA + 1, W2 - 1);
        float iwA = 1.0f - fwA;

        float swB = 0.5f * pB - 0.25f;
        float flwB = floorf(swB);
        float fwB = swB - flwB;
        int j0B = max((int)flwB, 0);
        int j1B = min((int)flwB + 1, W2 - 1);
        float iwB = 1.0f - fwB;

        const float4 RaA = *(const float4*)(Rs + j0A * 16 + cc);
        const float4 RbA = *(const float4*)(Rs + j1A * 16 + cc);
        const float4 CaA = *(const float4*)(Cs + j0A * 16 + cc);
        const float4 CbA = *(const float4*)(Cs + j1A * 16 + cc);
        const float4 RaB = *(const float4*)(Rs + j0B * 16 + cc);
        const float4 RbB = *(const float4*)(Rs + j1B * 16 + cc);
        const float4 CaB = *(const float4*)(Cs + j0B * 16 + cc);
        const float4 CbB = *(const float4*)(Cs + j1B * 16 + cc);

        float4 drA = make_float4(vA.x - (iwA * RaA.x + fwA * RbA.x),
                                 vA.y - (iwA * RaA.y + fwA * RbA.y),
                                 vA.z - (iwA * RaA.z + fwA * RbA.z),
                                 vA.w - (iwA * RaA.w + fwA * RbA.w));
        float4 dcA = make_float4(vA.x - (iwA * CaA.x + fwA * CbA.x),
                                 vA.y - (iwA * CaA.y + fwA * CbA.y),
                                 vA.z - (iwA * CaA.z + fwA * CbA.z),
                                 vA.w - (iwA * CaA.w + fwA * CbA.w));
        float4 drB = make_float4(vB.x - (iwB * RaB.x + fwB * RbB.x),
                                 vB.y - (iwB * RaB.y + fwB * RbB.y),
                                 vB.z - (iwB * RaB.z + fwB * RbB.z),
                                 vB.w - (iwB * RaB.w + fwB * RbB.w));
        float4 dcB = make_float4(vB.x - (iwB * CaB.x + fwB * CbB.x),
                                 vB.y - (iwB * CaB.y + fwB * CbB.y),
                                 vB.z - (iwB * CaB.z + fwB * CbB.z),
                                 vB.w - (iwB * CaB.w + fwB * CbB.w));

        orow[pA * 12 + cq]     = vA;
        orow[pA * 12 + 4 + cq] = drA;
        orow[pA * 12 + 8 + cq] = dcA;
        orow[pB * 12 + cq]     = vB;
        orow[pB * 12 + 4 + cq] = drB;
        orow[pB * 12 + 8 + cq] = dcB;
    }
}

extern "C" void kernel_launch(void* const* d_in, const int* in_sizes, int n_in,
                              void* d_out, int out_size, void* d_ws, size_t ws_size,
                              hipStream_t stream) {
    const float* fm   = (const float*)d_in[0];
    const float* kern = (const float*)d_in[1];
    const float* bias = (const float*)d_in[2];
    float* out = (float*)d_out;
    float* PP  = (float*)d_ws;                 // 2 x POOL_ELEMS partials
    float* ROW = PP + 2 * POOL_ELEMS;
    float* COL = ROW + POOL_ELEMS;

    pool_kernel<<<B * NP * CH * 2, 256, 0, stream>>>(fm, PP);
    conv_kernel<<<512, 256, 0, stream>>>(PP, kern, bias, ROW, COL);
    up_kernel<<<B * H, 256, 0, stream>>>(fm, ROW, COL, out);
}